// Round 4
// baseline (177.257 us; speedup 1.0000x reference)
//
#include <hip/hip_runtime.h>
#include <hip/hip_bf16.h>

typedef __attribute__((ext_vector_type(8))) short short8;
typedef __attribute__((ext_vector_type(4))) float f32x4;

static __device__ __forceinline__ unsigned short f2bf(float f){
  union { float f; unsigned int u; } v; v.f = f;
  unsigned int r = v.u + 0x7fffu + ((v.u >> 16) & 1u);
  return (unsigned short)(r >> 16);
}

static __device__ __forceinline__ void load_lds16(const unsigned short* g, unsigned short* l){
  __builtin_amdgcn_global_load_lds(
      (const __attribute__((address_space(1))) unsigned int*)(g),
      (__attribute__((address_space(3))) unsigned int*)(l), 16, 0, 0);
}

// ---------------- kernel 1: x fp32 -> bf16 ----------------
__global__ void k_cvt_x(const float* __restrict__ x, unsigned short* __restrict__ xb){
  int i = (blockIdx.x * 256 + threadIdx.x) * 8;
  float4 a = *(const float4*)(x + i);
  float4 b = *(const float4*)(x + i + 4);
  unsigned short h[8];
  h[0]=f2bf(a.x); h[1]=f2bf(a.y); h[2]=f2bf(a.z); h[3]=f2bf(a.w);
  h[4]=f2bf(b.x); h[5]=f2bf(b.y); h[6]=f2bf(b.z); h[7]=f2bf(b.w);
  *(uint4*)(xb + i) = *(uint4*)h;
}

// ---------------- kernel 2: W -> Wt bf16 [p][d][e], bias concat ----------------
__global__ void k_prep_w(const float* __restrict__ Wq, const float* __restrict__ Wk,
                         const float* __restrict__ Wv,
                         const float* __restrict__ bq, const float* __restrict__ bk,
                         const float* __restrict__ bv,
                         unsigned short* __restrict__ Wt, float* __restrict__ bias){
  int gid = blockIdx.x * 256 + threadIdx.x;    // 0 .. 393215
  int p = gid >> 17;
  int rem = gid & 131071;
  int d = rem >> 10, e = rem & 1023;
  const float* W = (p==0) ? Wq : ((p==1) ? Wk : Wv);
  Wt[gid] = f2bf(W[e*128 + d]);                 // Wt[p][d][e] = W[e][d]
  if (gid < 384){
    int pp = gid >> 7, dd = gid & 127;
    bias[gid] = (pp==0) ? bq[dd] : ((pp==1) ? bk[dd] : bv[dd]);
  }
}

// ---------------- kernel 3: fused QKV GEMM, 64x128 tiles, global_load_lds ------
// 384 blocks (128 m-tiles x 3 proj) -> 1.5 blocks/CU for latency overlap.
// Epilogue writes MFMA-fragment-linear swizzled layouts:
//   Qsw/Ksw: [rowtile16][kc(4)][quad(4)][l16(16)][8]
//   Vsw:     [b][t64][nt(8)][kc2(2)][quad(4)][l16(16)][8]
__global__ __launch_bounds__(256) void k_gemm_qkv(
    const unsigned short* __restrict__ Xb, const unsigned short* __restrict__ Wt,
    const float* __restrict__ bias,
    unsigned short* __restrict__ Qsw, unsigned short* __restrict__ Ksw,
    unsigned short* __restrict__ Vsw){
  __shared__ __align__(16) unsigned short As[64*64];    // 8 KB
  __shared__ __align__(16) unsigned short Bs[128*64];   // 16 KB
  int tid = threadIdx.x;
  int m0 = blockIdx.x * 64;
  int p  = blockIdx.y;
  int w = tid >> 6, lane = tid & 63, quad = lane >> 4, l16 = lane & 15;
  int wm = (w >> 1) * 32, wn = (w & 1) * 64;
  f32x4 acc[2][4];
  #pragma unroll
  for (int i=0;i<2;i++)
    #pragma unroll
    for (int j=0;j<4;j++) acc[i][j] = (f32x4){0.f,0.f,0.f,0.f};

  const unsigned short* Wp = Wt + p * (128*1024);
  // wave w stages A rows [w*16, w*16+16) and B rows [w*32, w*32+32)
  const unsigned short* Ag = Xb + (m0 + w*16 + (lane>>3))*1024 + (lane&7)*8;
  const unsigned short* Bg = Wp + (w*32 + (lane>>3))*1024 + (lane&7)*8;
  unsigned short* Al = As + w*16*64;   // wave-uniform base; HW adds lane*16B
  unsigned short* Bl = Bs + w*32*64;

  for (int k0 = 0; k0 < 1024; k0 += 64){
    load_lds16(Ag + k0,        Al);
    load_lds16(Ag + k0 + 8192, Al + 512);
    #pragma unroll
    for (int s=0; s<4; s++)
      load_lds16(Bg + k0 + s*8192, Bl + s*512);
    __syncthreads();
    #pragma unroll
    for (int kk=0; kk<64; kk+=32){
      short8 af[2], bf[4];
      #pragma unroll
      for (int i=0;i<2;i++) af[i] = *(const short8*)(As + (wm + i*16 + l16)*64 + kk + quad*8);
      #pragma unroll
      for (int j=0;j<4;j++) bf[j] = *(const short8*)(Bs + (wn + j*16 + l16)*64 + kk + quad*8);
      #pragma unroll
      for (int i=0;i<2;i++)
        #pragma unroll
        for (int j=0;j<4;j++)
          acc[i][j] = __builtin_amdgcn_mfma_f32_16x16x32_bf16(af[i], bf[j], acc[i][j], 0,0,0);
    }
    __syncthreads();
  }
  const float qscale = 0.08838834764831845f;  // 1/sqrt(128) folded into Q
  #pragma unroll
  for (int i=0;i<2;i++){
    #pragma unroll
    for (int j=0;j<4;j++){
      int c = wn + j*16 + l16;             // 0..127
      float bv_ = bias[p*128 + c];
      #pragma unroll
      for (int r=0;r<4;r++){
        int row = m0 + wm + i*16 + quad*4 + r;
        float v = acc[i][j][r] + bv_;
        if (p == 0){
          int rt = row >> 4, m = row & 15;
          int kc = c >> 5, q2 = (c >> 3) & 3, jj = c & 7;
          Qsw[rt*2048 + kc*512 + q2*128 + m*8 + jj] = f2bf(v * qscale);
        } else if (p == 1){
          int kt = row >> 4, n = row & 15;
          int kc = c >> 5, q2 = (c >> 3) & 3, jj = c & 7;
          Ksw[kt*2048 + kc*512 + q2*128 + n*8 + jj] = f2bf(v);
        } else {
          int b = row >> 11, s = row & 2047;
          int t64 = s >> 6, srem = s & 63;
          int kc2 = srem >> 5, q2 = (srem >> 3) & 3, jj = srem & 7;
          int nt = c >> 4, l2 = c & 15;
          Vsw[(b*32 + t64)*8192 + nt*1024 + kc2*512 + q2*128 + l2*8 + jj] = f2bf(v);
        }
      }
    }
  }
}

// ---------------- kernel 4: causal flash attention ----------------
// 256 blocks x 512 threads. Block = 32 q-rows (2 subtiles of 16) x 4 kv-phases.
// XCD swizzle: batch = (blockIdx.x & 7) >> 1  -> each batch pinned to 2 XCDs,
// per-XCD K/V working set 3 MB < 4 MB L2. All fragment loads contiguous 1KB.
__global__ __launch_bounds__(512, 4) void k_attn(
    const unsigned short* __restrict__ Qsw, const unsigned short* __restrict__ Ksw,
    const unsigned short* __restrict__ Vsw, float* __restrict__ out){
  __shared__ __align__(16) float LDSo[8*16*128];   // 64 KB partial O (+aliased P scratch)
  __shared__ float Lm[8*16];
  __shared__ float Ll[8*16];
  int tid = threadIdx.x;
  int x = blockIdx.x;                 // 0..255
  int b = (x & 7) >> 1;               // 2 XCDs per batch
  int qpair = (x >> 3) * 2 + (x & 1); // 0..63
  int qblk = 63 - qpair;              // heavy q-blocks dispatched first
  int qbase = qblk * 32;
  int w = tid >> 6, lane = tid & 63, quad = lane >> 4, l16 = lane & 15;
  int qsub = w & 1, ph = w >> 1;      // wave -> (q-subtile, kv-phase)
  int q0 = qbase + qsub * 16;
  int qt16 = (qbase >> 4) + qsub;

  short8 aq[4];
  #pragma unroll
  for (int kc=0; kc<4; kc++)
    aq[kc] = *(const short8*)(Qsw + (b*128 + qt16)*2048 + kc*512 + lane*8);

  f32x4 o[8];
  #pragma unroll
  for (int i=0;i<8;i++) o[i] = (f32x4){0.f,0.f,0.f,0.f};
  float mrow[4] = {-1e30f,-1e30f,-1e30f,-1e30f};
  float lrow[4] = {0.f,0.f,0.f,0.f};

  int T = (q0 >> 6) + 1;
  unsigned short* Pw = (unsigned short*)(LDSo + w*2048);

  const unsigned short* Kb = Ksw + b*128*2048;
  const unsigned short* Vb = Vsw + b*32*8192;

  for (int t = ph; t < T; t += 4){
    int t0 = t*64;
    // S = Q @ K^T
    f32x4 sc[4];
    #pragma unroll
    for (int nt=0;nt<4;nt++) sc[nt] = (f32x4){0.f,0.f,0.f,0.f};
    #pragma unroll
    for (int nt=0;nt<4;nt++){
      const unsigned short* Kt = Kb + ((t0>>4) + nt)*2048 + lane*8;
      #pragma unroll
      for (int kc=0;kc<4;kc++){
        short8 bf = *(const short8*)(Kt + kc*512);
        sc[nt] = __builtin_amdgcn_mfma_f32_16x16x32_bf16(aq[kc], bf, sc[nt], 0,0,0);
      }
    }

    // causal mask + online softmax (rows = quad*4+r, key cols = t0 + nt*16 + l16)
    float mt[4] = {-1e30f,-1e30f,-1e30f,-1e30f};
    #pragma unroll
    for (int nt=0;nt<4;nt++){
      int key = t0 + nt*16 + l16;
      #pragma unroll
      for (int r=0;r<4;r++){
        int qr = q0 + quad*4 + r;
        float s = sc[nt][r];
        s = (key > qr) ? -1e30f : s;
        sc[nt][r] = s;
        mt[r] = fmaxf(mt[r], s);
      }
    }
    #pragma unroll
    for (int r=0;r<4;r++){
      mt[r] = fmaxf(mt[r], __shfl_xor(mt[r], 1));
      mt[r] = fmaxf(mt[r], __shfl_xor(mt[r], 2));
      mt[r] = fmaxf(mt[r], __shfl_xor(mt[r], 4));
      mt[r] = fmaxf(mt[r], __shfl_xor(mt[r], 8));
    }
    float alpha[4], rs[4];
    #pragma unroll
    for (int r=0;r<4;r++){
      float mn = fmaxf(mrow[r], mt[r]);
      alpha[r] = __expf(mrow[r] - mn);
      mrow[r] = mn;
      rs[r] = 0.f;
    }
    #pragma unroll
    for (int nt=0;nt<4;nt++)
      #pragma unroll
      for (int r=0;r<4;r++){
        float pv = __expf(sc[nt][r] - mrow[r]);
        sc[nt][r] = pv;
        rs[r] += pv;
      }
    #pragma unroll
    for (int r=0;r<4;r++){
      rs[r] += __shfl_xor(rs[r], 1);
      rs[r] += __shfl_xor(rs[r], 2);
      rs[r] += __shfl_xor(rs[r], 4);
      rs[r] += __shfl_xor(rs[r], 8);
      lrow[r] = lrow[r]*alpha[r] + rs[r];
    }
    #pragma unroll
    for (int i=0;i<8;i++)
      #pragma unroll
      for (int r=0;r<4;r++) o[i][r] *= alpha[r];

    // P: C-layout -> A-layout via per-wave LDS scratch (same-wave dep, no barrier)
    #pragma unroll
    for (int nt=0;nt<4;nt++)
      #pragma unroll
      for (int r=0;r<4;r++)
        Pw[(quad*4+r)*72 + nt*16 + l16] = f2bf(sc[nt][r]);
    short8 ap[2];
    #pragma unroll
    for (int kc2=0; kc2<2; kc2++)
      ap[kc2] = *(const short8*)(Pw + l16*72 + kc2*32 + quad*8);

    // O += P @ V
    const unsigned short* Vt0 = Vb + (t0>>6)*8192 + lane*8;
    #pragma unroll
    for (int nt=0; nt<8; nt++)
      #pragma unroll
      for (int kc2=0;kc2<2;kc2++){
        short8 bf = *(const short8*)(Vt0 + nt*1024 + kc2*512);
        o[nt] = __builtin_amdgcn_mfma_f32_16x16x32_bf16(ap[kc2], bf, o[nt], 0,0,0);
      }
  }

  // deposit per-wave partials
  #pragma unroll
  for (int i=0;i<8;i++)
    #pragma unroll
    for (int r=0;r<4;r++)
      LDSo[w*2048 + (quad*4+r)*128 + i*16 + l16] = o[i][r];
  if (l16 == 0){
    #pragma unroll
    for (int r=0;r<4;r++){
      Lm[w*16 + quad*4 + r] = mrow[r];
      Ll[w*16 + quad*4 + r] = lrow[r];
    }
  }
  __syncthreads();

  // combine 4 kv-phase partials per q-subtile
  int r  = tid >> 4;               // 0..31 (output row within block)
  int c0 = (tid & 15) * 8;         // 0..120
  int qs2 = r >> 4, row16 = r & 15;
  float m = -1e30f;
  #pragma unroll
  for (int p4=0; p4<4; p4++) m = fmaxf(m, Lm[(p4*2+qs2)*16 + row16]);
  float a0=0,a1=0,a2=0,a3=0,a4=0,a5=0,a6=0,a7=0, lsum=0;
  #pragma unroll
  for (int p4=0; p4<4; p4++){
    int ww = p4*2 + qs2;
    float e = __expf(Lm[ww*16 + row16] - m);
    lsum += Ll[ww*16 + row16] * e;
    f32x4 o1 = *(const f32x4*)(LDSo + ww*2048 + row16*128 + c0);
    f32x4 o2 = *(const f32x4*)(LDSo + ww*2048 + row16*128 + c0 + 4);
    a0 += o1[0]*e; a1 += o1[1]*e; a2 += o1[2]*e; a3 += o1[3]*e;
    a4 += o2[0]*e; a5 += o2[1]*e; a6 += o2[2]*e; a7 += o2[3]*e;
  }
  float inv = 1.0f / lsum;
  float4 r1 = {a0*inv, a1*inv, a2*inv, a3*inv};
  float4 r2 = {a4*inv, a5*inv, a6*inv, a7*inv};
  float* op = out + (b*2048 + qbase + r)*128 + c0;
  *(float4*)(op)     = r1;
  *(float4*)(op + 4) = r2;
}

extern "C" void kernel_launch(void* const* d_in, const int* in_sizes, int n_in,
                              void* d_out, int out_size, void* d_ws, size_t ws_size,
                              hipStream_t stream) {
  const float* x  = (const float*)d_in[0];
  const float* Wq = (const float*)d_in[1];
  const float* bq = (const float*)d_in[2];
  const float* Wk = (const float*)d_in[3];
  const float* bk = (const float*)d_in[4];
  const float* Wv = (const float*)d_in[5];
  const float* bv = (const float*)d_in[6];
  char* ws = (char*)d_ws;
  unsigned short* Xb = (unsigned short*)(ws);               // 16,777,216 B
  unsigned short* Wt = (unsigned short*)(ws + 16777216);    //    786,432 B
  float*          bias = (float*)(ws + 17563648);           //      1,536 B
  unsigned short* Qsw = (unsigned short*)(ws + 17565184);   //  2,097,152 B
  unsigned short* Ksw = (unsigned short*)(ws + 19662336);   //  2,097,152 B
  unsigned short* Vsw = (unsigned short*)(ws + 21759488);   //  2,097,152 B
  float* out = (float*)d_out;

  hipLaunchKernelGGL(k_cvt_x,   dim3(4096),  dim3(256), 0, stream, x, Xb);
  hipLaunchKernelGGL(k_prep_w,  dim3(1536),  dim3(256), 0, stream, Wq, Wk, Wv, bq, bk, bv, Wt, bias);
  hipLaunchKernelGGL(k_gemm_qkv,dim3(128,3), dim3(256), 0, stream, Xb, Wt, bias, Qsw, Ksw, Vsw);
  hipLaunchKernelGGL(k_attn,    dim3(256),   dim3(512), 0, stream, Qsw, Ksw, Vsw, out);
}

// Round 6
// 139.742 us; speedup vs baseline: 1.2685x; 1.2685x over previous
//
#include <hip/hip_runtime.h>
#include <hip/hip_bf16.h>

typedef __attribute__((ext_vector_type(8))) short short8;
typedef __attribute__((ext_vector_type(4))) float f32x4;

static __device__ __forceinline__ unsigned short f2bf(float f){
  union { float f; unsigned int u; } v; v.f = f;
  unsigned int r = v.u + 0x7fffu + ((v.u >> 16) & 1u);
  return (unsigned short)(r >> 16);
}

static __device__ __forceinline__ void load_lds16(const unsigned short* g, unsigned short* l){
  __builtin_amdgcn_global_load_lds(
      (const __attribute__((address_space(1))) unsigned int*)(g),
      (__attribute__((address_space(3))) unsigned int*)(l), 16, 0, 0);
}

// ---------------- kernel 1: x fp32 -> bf16 ----------------
__global__ void k_cvt_x(const float* __restrict__ x, unsigned short* __restrict__ xb){
  int i = (blockIdx.x * 256 + threadIdx.x) * 8;
  float4 a = *(const float4*)(x + i);
  float4 b = *(const float4*)(x + i + 4);
  unsigned short h[8];
  h[0]=f2bf(a.x); h[1]=f2bf(a.y); h[2]=f2bf(a.z); h[3]=f2bf(a.w);
  h[4]=f2bf(b.x); h[5]=f2bf(b.y); h[6]=f2bf(b.z); h[7]=f2bf(b.w);
  *(uint4*)(xb + i) = *(uint4*)h;
}

// ---------------- kernel 2: W -> Wt bf16 [p][d][e], bias concat ----------------
__global__ void k_prep_w(const float* __restrict__ Wq, const float* __restrict__ Wk,
                         const float* __restrict__ Wv,
                         const float* __restrict__ bq, const float* __restrict__ bk,
                         const float* __restrict__ bv,
                         unsigned short* __restrict__ Wt, float* __restrict__ bias){
  int gid = blockIdx.x * 256 + threadIdx.x;    // 0 .. 393215
  int p = gid >> 17;
  int rem = gid & 131071;
  int d = rem >> 10, e = rem & 1023;
  const float* W = (p==0) ? Wq : ((p==1) ? Wk : Wv);
  Wt[gid] = f2bf(W[e*128 + d]);                 // Wt[p][d][e] = W[e][d]
  if (gid < 384){
    int pp = gid >> 7, dd = gid & 127;
    bias[gid] = (pp==0) ? bq[dd] : ((pp==1) ? bk[dd] : bv[dd]);
  }
}

// ---------------- kernel 3a: QKV GEMM, split-K=2, f32 partials ----------------
// grid (64 mt, 3 p, 2 kh); 128x128 tile, K-half = 512 (8 iters of 64).
__global__ __launch_bounds__(256) void k_gemm_qkv(
    const unsigned short* __restrict__ Xb, const unsigned short* __restrict__ Wt,
    float* __restrict__ Cp){
  __shared__ __align__(16) unsigned short As[128*64];
  __shared__ __align__(16) unsigned short Bs[128*64];
  int tid = threadIdx.x;
  int m0 = blockIdx.x * 128;
  int p  = blockIdx.y;
  int kh = blockIdx.z;
  int w = tid >> 6, lane = tid & 63, quad = lane >> 4, l16 = lane & 15;
  int wm = (w >> 1) * 64, wn = (w & 1) * 64;
  f32x4 acc[4][4];
  #pragma unroll
  for (int i=0;i<4;i++)
    #pragma unroll
    for (int j=0;j<4;j++) acc[i][j] = (f32x4){0.f,0.f,0.f,0.f};

  const unsigned short* Wp = Wt + p * (128*1024);
  int rowbase = w * 32;
  const unsigned short* Ag = Xb + (m0 + rowbase + (lane>>3))*1024 + (lane&7)*8;
  const unsigned short* Bg = Wp + (rowbase + (lane>>3))*1024 + (lane&7)*8;
  unsigned short* Al = As + rowbase*64;   // wave-uniform base; HW adds lane*16B
  unsigned short* Bl = Bs + rowbase*64;

  int kbeg = kh*512, kend = kbeg + 512;
  for (int k0 = kbeg; k0 < kend; k0 += 64){
    #pragma unroll
    for (int s8=0; s8<4; s8++){
      load_lds16(Ag + k0 + s8*8192, Al + s8*512);
      load_lds16(Bg + k0 + s8*8192, Bl + s8*512);
    }
    __syncthreads();
    #pragma unroll
    for (int kk=0; kk<64; kk+=32){
      short8 af[4], bf[4];
      #pragma unroll
      for (int i=0;i<4;i++) af[i] = *(const short8*)(As + (wm + i*16 + l16)*64 + kk + quad*8);
      #pragma unroll
      for (int j=0;j<4;j++) bf[j] = *(const short8*)(Bs + (wn + j*16 + l16)*64 + kk + quad*8);
      #pragma unroll
      for (int i=0;i<4;i++)
        #pragma unroll
        for (int j=0;j<4;j++)
          acc[i][j] = __builtin_amdgcn_mfma_f32_16x16x32_bf16(af[i], bf[j], acc[i][j], 0,0,0);
    }
    __syncthreads();
  }
  float* slot = Cp + (size_t)(((p*64 + blockIdx.x)*2 + kh)) * 16384;
  #pragma unroll
  for (int i=0;i<4;i++)
    #pragma unroll
    for (int j=0;j<4;j++)
      #pragma unroll
      for (int r=0;r<4;r++)
        slot[(wm + i*16 + quad*4 + r)*128 + wn + j*16 + l16] = acc[i][j][r];
}

// ---------------- kernel 3b: combine split-K + bias + swizzled bf16 stores ----
//   Qsw/Ksw: [rowtile16][kc(4)][quad(4)][l16(16)][8]
//   Vsw:     [b][t64][nt(8)][kc2(2)][quad(4)][l16(16)][8]
__global__ __launch_bounds__(256) void k_gcomb(const float* __restrict__ Cp,
    const float* __restrict__ bias,
    unsigned short* __restrict__ Qsw, unsigned short* __restrict__ Ksw,
    unsigned short* __restrict__ Vsw){
  int mt = blockIdx.x, p = blockIdx.y, tid = threadIdx.x;
  const float* c0p = Cp + (size_t)((p*64+mt)*2) * 16384;
  const float* c1p = c0p + 16384;
  int m0 = mt*128;
  const float qscale = 0.08838834764831845f;  // 1/sqrt(128)
  if (p < 2){
    unsigned short* dst = (p==0)? Qsw : Ksw;
    float scale = (p==0)? qscale : 1.0f;
    for (int it=0; it<16; it++){
      int g = it*256 + tid;            // 0..4095
      int row = g >> 5, cs = (g & 31)*4;
      f32x4 a = *(const f32x4*)(c0p + row*128 + cs);
      f32x4 bb = *(const f32x4*)(c1p + row*128 + cs);
      int grow = m0 + row;
      int rt = grow >> 4, m = grow & 15;
      int kc = cs >> 5, q2 = (cs >> 3) & 3, jj = cs & 7;
      unsigned short pk[4];
      #pragma unroll
      for (int k=0;k<4;k++) pk[k] = f2bf((a[k]+bb[k]+bias[p*128+cs+k])*scale);
      *(uint2*)(dst + rt*2048 + kc*512 + q2*128 + m*8 + jj) = *(uint2*)pk;
    }
  } else {
    for (int it=0; it<16; it++){
      int g = it*256 + tid;
      int col = g & 127, rg = g >> 7;   // 32 row-groups of 4
      int r0 = rg*4;
      float bv_ = bias[256 + col];
      unsigned short pk[4];
      #pragma unroll
      for (int k=0;k<4;k++){
        int row = r0 + k;
        pk[k] = f2bf(c0p[row*128+col] + c1p[row*128+col] + bv_);
      }
      int grow0 = m0 + r0;
      int bb2 = grow0 >> 11, s = grow0 & 2047;
      int t64 = s >> 6, srem = s & 63;
      int kc2 = srem >> 5, q2 = (srem >> 3) & 3, jj = srem & 7;
      int nt = col >> 4, l2 = col & 15;
      *(uint2*)(Vsw + (bb2*32+t64)*8192 + nt*1024 + kc2*512 + q2*128 + l2*8 + jj) = *(uint2*)pk;
    }
  }
}

// ---------------- kernel 4a: attention partial, flat jobs, 1-wave blocks -------
// Job = (b, 32 q-rows, chunk of <=4 kv-tiles). S^T = K@Q^T so softmax reductions
// are in-register (+2 shuffles). K/V fragments shared across the 2 q-subtiles.
// Writes partial (O[32][128], m[32], l[32]) to Apart slot.
__global__ __launch_bounds__(64) void k_attn(
    const unsigned short* __restrict__ Qsw, const unsigned short* __restrict__ Ksw,
    const unsigned short* __restrict__ Vsw, float* __restrict__ Apart){
  __shared__ __align__(16) unsigned short Pw[2*16*80];
  int x = blockIdx.x;
  int b = x & 3;
  int t = x >> 2;
  int c = t & 7;
  int qb = 63 - (t >> 3);              // heavy q-blocks first
  int T32 = (qb >> 1) + 1;             // kv tiles covering keys <= qb*32+31
  int nch = (T32 + 3) >> 2;
  if (c >= nch) return;
  int lane = threadIdx.x;
  int quad = lane >> 4, l16 = lane & 15;
  int q0 = qb * 32;

  short8 aq[2][4];
  #pragma unroll
  for (int s=0;s<2;s++)
    #pragma unroll
    for (int kc=0;kc<4;kc++)
      aq[s][kc] = *(const short8*)(Qsw + (b*128 + qb*2 + s)*2048 + kc*512 + lane*8);

  f32x4 o[2][8];
  #pragma unroll
  for (int s=0;s<2;s++)
    #pragma unroll
    for (int i=0;i<8;i++) o[s][i] = (f32x4){0.f,0.f,0.f,0.f};
  float mcol[2] = {-1e30f,-1e30f};
  float lcol[2] = {0.f,0.f};
  short8 ap[2][2];

  const unsigned short* Kb = Ksw + b*128*2048;
  const unsigned short* Vb = Vsw + b*32*8192;

  int tEnd = (T32 < c*4+4) ? T32 : (c*4+4);
  for (int tt = c*4; tt < tEnd; tt++){
    int t0 = tt * 64;
    // S^T = K @ Q^T : A = K frags (m=key), B = Q frags (n=q). C: row=key, col=q.
    f32x4 sc[2][4];
    #pragma unroll
    for (int s=0;s<2;s++)
      #pragma unroll
      for (int nt=0;nt<4;nt++) sc[s][nt] = (f32x4){0.f,0.f,0.f,0.f};
    #pragma unroll
    for (int nt=0;nt<4;nt++){
      const unsigned short* Kt = Kb + ((t0>>4)+nt)*2048 + lane*8;
      #pragma unroll
      for (int kc=0;kc<4;kc++){
        short8 kf = *(const short8*)(Kt + kc*512);
        sc[0][nt] = __builtin_amdgcn_mfma_f32_16x16x32_bf16(kf, aq[0][kc], sc[0][nt], 0,0,0);
        sc[1][nt] = __builtin_amdgcn_mfma_f32_16x16x32_bf16(kf, aq[1][kc], sc[1][nt], 0,0,0);
      }
    }
    #pragma unroll
    for (int s=0;s<2;s++){
      int qs = q0 + s*16;               // q rows qs..qs+15; our q col = qs + l16
      if (t0 + 63 > qs){                // mask needed iff tile's max key > subtile's MIN q
        #pragma unroll
        for (int nt=0;nt<4;nt++){
          int kb_ = t0 + nt*16 + quad*4;
          #pragma unroll
          for (int r=0;r<4;r++)
            if (kb_ + r > qs + l16) sc[s][nt][r] = -1e30f;
        }
      }
      // in-register max over 16 keys, then 2 shuffles across quads
      float mt_ = -1e30f;
      #pragma unroll
      for (int nt=0;nt<4;nt++)
        #pragma unroll
        for (int r=0;r<4;r++) mt_ = fmaxf(mt_, sc[s][nt][r]);
      mt_ = fmaxf(mt_, __shfl_xor(mt_, 16));
      mt_ = fmaxf(mt_, __shfl_xor(mt_, 32));
      float mn = fmaxf(mcol[s], mt_);
      float al = __expf(mcol[s] - mn);
      mcol[s] = mn;
      float ls = 0.f;
      #pragma unroll
      for (int nt=0;nt<4;nt++)
        #pragma unroll
        for (int r=0;r<4;r++){
          float pv = __expf(sc[s][nt][r] - mn);
          sc[s][nt][r] = pv;
          ls += pv;
        }
      ls += __shfl_xor(ls, 16);
      ls += __shfl_xor(ls, 32);
      lcol[s] = lcol[s]*al + ls;
      // rescale O: alpha indexed by q-row = quad*4+r -> fetch from lane l16=quad*4+r
      #pragma unroll
      for (int r=0;r<4;r++){
        float ar = __shfl(al, quad*4 + r);
        #pragma unroll
        for (int nt=0;nt<8;nt++) o[s][nt][r] *= ar;
      }
      // P^T (C-layout) -> P A-layout: packed b64 writes then b128 reads
      unsigned short* Pws = Pw + s*1280;
      #pragma unroll
      for (int nt=0;nt<4;nt++){
        unsigned short pk[4];
        #pragma unroll
        for (int r=0;r<4;r++) pk[r] = f2bf(sc[s][nt][r]);
        *(uint2*)(Pws + l16*80 + nt*16 + quad*4) = *(uint2*)pk;
      }
      ap[s][0] = *(const short8*)(Pws + l16*80 + quad*8);
      ap[s][1] = *(const short8*)(Pws + l16*80 + 32 + quad*8);
    }
    // O += P @ V ; V fragments shared by both subtiles
    const unsigned short* Vt0 = Vb + (t0>>6)*8192 + lane*8;
    #pragma unroll
    for (int nt=0; nt<8; nt++)
      #pragma unroll
      for (int kc2=0;kc2<2;kc2++){
        short8 vf = *(const short8*)(Vt0 + nt*1024 + kc2*512);
        o[0][nt] = __builtin_amdgcn_mfma_f32_16x16x32_bf16(ap[0][kc2], vf, o[0][nt], 0,0,0);
        o[1][nt] = __builtin_amdgcn_mfma_f32_16x16x32_bf16(ap[1][kc2], vf, o[1][nt], 0,0,0);
      }
  }

  float* slot = Apart + (size_t)(((b*64 + qb)*8 + c)) * 4160;
  #pragma unroll
  for (int s=0;s<2;s++){
    #pragma unroll
    for (int nt=0;nt<8;nt++)
      #pragma unroll
      for (int r=0;r<4;r++)
        slot[(s*16 + quad*4 + r)*128 + nt*16 + l16] = o[s][nt][r];
    if (quad == 0){
      slot[4096 + s*16 + l16] = mcol[s];
      slot[4128 + s*16 + l16] = lcol[s];
    }
  }
}

// ---------------- kernel 4b: combine attention chunks ----------------
__global__ __launch_bounds__(256) void k_acomb(const float* __restrict__ Apart,
                                               float* __restrict__ out){
  int b = blockIdx.x & 3, qb = blockIdx.x >> 2;
  int T32 = (qb >> 1) + 1;
  int nch = (T32 + 3) >> 2;
  const float* base = Apart + (size_t)((b*64 + qb)*8) * 4160;
  int tid = threadIdx.x;
  int row = tid >> 3;              // 0..31
  int c0 = (tid & 7) * 16;         // 16 cols per thread
  float m = -1e30f;
  for (int c=0;c<nch;c++) m = fmaxf(m, base[c*4160 + 4096 + row]);
  f32x4 acc[4];
  #pragma unroll
  for (int g=0;g<4;g++) acc[g] = (f32x4){0.f,0.f,0.f,0.f};
  float lsum = 0.f;
  for (int c=0;c<nch;c++){
    float e = __expf(base[c*4160 + 4096 + row] - m);
    lsum += base[c*4160 + 4128 + row] * e;
    #pragma unroll
    for (int g=0;g<4;g++){
      f32x4 v = *(const f32x4*)(base + c*4160 + row*128 + c0 + g*4);
      acc[g] += v * e;
    }
  }
  float inv = 1.0f / lsum;
  float* op = out + (size_t)(b*2048 + qb*32 + row)*128 + c0;
  #pragma unroll
  for (int g=0;g<4;g++){
    f32x4 r = acc[g] * inv;
    *(f32x4*)(op + g*4) = r;
  }
}

extern "C" void kernel_launch(void* const* d_in, const int* in_sizes, int n_in,
                              void* d_out, int out_size, void* d_ws, size_t ws_size,
                              hipStream_t stream) {
  const float* x  = (const float*)d_in[0];
  const float* Wq = (const float*)d_in[1];
  const float* bq = (const float*)d_in[2];
  const float* Wk = (const float*)d_in[3];
  const float* bk = (const float*)d_in[4];
  const float* Wv = (const float*)d_in[5];
  const float* bv = (const float*)d_in[6];
  char* ws = (char*)d_ws;
  unsigned short* Xb   = (unsigned short*)(ws);             // 16,777,216 B
  unsigned short* Wt   = (unsigned short*)(ws + 16777216);  //    786,432 B
  float*          bias = (float*)(ws + 17563648);           //      1,536 B
  unsigned short* Qsw  = (unsigned short*)(ws + 17565184);  //  2,097,152 B
  unsigned short* Ksw  = (unsigned short*)(ws + 19662336);  //  2,097,152 B
  unsigned short* Vsw  = (unsigned short*)(ws + 21759488);  //  2,097,152 B
  float*          Cp   = (float*)(ws + 23856640);           // 25,165,824 B (384 x 64KB)
  float*          Apart= (float*)(ws + 49022464);           // 34,078,720 B (2048 x 16.6KB)
  float* out = (float*)d_out;

  hipLaunchKernelGGL(k_cvt_x,   dim3(4096),    dim3(256), 0, stream, x, Xb);
  hipLaunchKernelGGL(k_prep_w,  dim3(1536),    dim3(256), 0, stream, Wq, Wk, Wv, bq, bk, bv, Wt, bias);
  hipLaunchKernelGGL(k_gemm_qkv,dim3(64,3,2),  dim3(256), 0, stream, Xb, Wt, Cp);
  hipLaunchKernelGGL(k_gcomb,   dim3(64,3),    dim3(256), 0, stream, Cp, bias, Qsw, Ksw, Vsw);
  hipLaunchKernelGGL(k_attn,    dim3(2048),    dim3(64),  0, stream, Qsw, Ksw, Vsw, Apart);
  hipLaunchKernelGGL(k_acomb,   dim3(256),     dim3(256), 0, stream, Apart, out);
}